// Round 1
// baseline (1778.988 us; speedup 1.0000x reference)
//
#include <hip/hip_runtime.h>
#include <cstddef>

#define NB  4
#define NC  256
#define NN  4096
#define DQK 32
#define MT  64      // query tile per block
#define JT  32      // key tile per iteration
#define VSTR 34     // Vs row stride (words): 34 => bank = (2c+2j)%32, 2-way max (free)
#define PSTR 34     // Ps row stride (words)

// ---------------- q/k projections: q[b][n][o], kT[b][n][o] ----------------
__global__ __launch_bounds__(256) void proj_qk_kernel(
    const float* __restrict__ x, const float* __restrict__ Wq,
    const float* __restrict__ bq, const float* __restrict__ Wk,
    const float* __restrict__ bk, float* __restrict__ q, float* __restrict__ kT) {
  const int t = threadIdx.x;
  const int b = blockIdx.y;
  const int n = blockIdx.x * 64 + (t & 63);
  // wave-uniform group id -> weight indices become SGPR-only -> scalar loads
  const int g = __builtin_amdgcn_readfirstlane(t >> 6);   // 0,1: q ; 2,3: k
  const float* W    = (g < 2) ? Wq : Wk;
  const float* bias = (g < 2) ? bq : bk;
  const int obase = (g & 1) * 16;

  float acc[16];
#pragma unroll
  for (int i = 0; i < 16; ++i) acc[i] = bias[obase + i];

  const float* xp = x + ((size_t)b * NC) * NN + n;
#pragma unroll 4
  for (int c = 0; c < NC; ++c) {
    float xv = xp[(size_t)c * NN];               // coalesced across lanes
#pragma unroll
    for (int i = 0; i < 16; ++i) acc[i] += W[(obase + i) * NC + c] * xv;
  }
  float* dst = ((g < 2) ? q : kT) + ((size_t)b * NN + n) * DQK + obase;
#pragma unroll
  for (int i = 0; i < 16; i += 4)
    *(float4*)(dst + i) = make_float4(acc[i], acc[i+1], acc[i+2], acc[i+3]);
}

// ---------------- v projection: v[b][o][n] ----------------
__global__ __launch_bounds__(256) void proj_v_kernel(
    const float* __restrict__ x, const float* __restrict__ Wv,
    const float* __restrict__ bv, float* __restrict__ v) {
  const int t = threadIdx.x;
  const int b = blockIdx.z;
  const int n = blockIdx.x * 64 + (t & 63);
  const int g = __builtin_amdgcn_readfirstlane(t >> 6);
  const int obase = blockIdx.y * 64 + g * 16;

  float acc[16];
#pragma unroll
  for (int i = 0; i < 16; ++i) acc[i] = bv[obase + i];

  const float* xp = x + ((size_t)b * NC) * NN + n;
#pragma unroll 4
  for (int c = 0; c < NC; ++c) {
    float xv = xp[(size_t)c * NN];
#pragma unroll
    for (int i = 0; i < 16; ++i) acc[i] += Wv[(obase + i) * NC + c] * xv;
  }
#pragma unroll
  for (int i = 0; i < 16; ++i)
    v[((size_t)b * NC + obase + i) * NN + n] = acc[i];   // coalesced in n
}

// ---------------- fused flash attention + gamma*out + x ----------------
__global__ __launch_bounds__(256, 1) void flash_kernel(
    const float* __restrict__ q, const float* __restrict__ kT,
    const float* __restrict__ v, const float* __restrict__ x,
    const float* __restrict__ gamma, float* __restrict__ out) {
  __shared__ float Vs[NC * VSTR];   // 34.8 KB
  __shared__ float Ps[MT * PSTR];   //  8.7 KB
  __shared__ float red[256];
  __shared__ float mrow[MT];
  __shared__ float lrow[MT];
  __shared__ float arow[MT];

  const int t  = threadIdx.x;
  const int b  = blockIdx.y;
  const int m0 = blockIdx.x * MT;
  const int sm = t & 63;                                   // S-phase row
  const int sgu = __builtin_amdgcn_readfirstlane(t >> 6);  // wave-uniform j-group
  const int tc = t & 31;                                   // PV c-group
  const int tm = t >> 5;                                   // PV m-group

  // Q row in registers (each lane holds its query row; waves hold duplicates)
  float qreg[DQK];
  {
    const float* qp = q + ((size_t)b * NN + m0 + sm) * DQK;
#pragma unroll
    for (int o = 0; o < DQK; o += 4) {
      float4 qq = *(const float4*)(qp + o);
      qreg[o] = qq.x; qreg[o+1] = qq.y; qreg[o+2] = qq.z; qreg[o+3] = qq.w;
    }
  }
  if (t < MT) { mrow[t] = -1e30f; lrow[t] = 0.f; }

  float oacc[8][8];
#pragma unroll
  for (int im = 0; im < 8; ++im)
#pragma unroll
    for (int ic = 0; ic < 8; ++ic) oacc[im][ic] = 0.f;

  for (int j0 = 0; j0 < NN; j0 += JT) {
    __syncthreads();  // barA: previous PV reads of Vs/Ps done; init visible

    // stage V tile [256c x 32j] -> LDS (coalesced float4 global reads)
    {
      const int cr = t >> 3;
      const int jc = (t & 7) * 4;
#pragma unroll
      for (int pass = 0; pass < 8; ++pass) {
        const int c = cr + pass * 32;
        float4 vv = *(const float4*)(v + ((size_t)b * NC + c) * NN + j0 + jc);
        float* dst = &Vs[c * VSTR + jc];
        *(float2*)(dst)     = make_float2(vv.x, vv.y);
        *(float2*)(dst + 2) = make_float2(vv.z, vv.w);
      }
    }

    // S[m][j] = q[m] . k[:,j]  — K via wave-uniform scalar loads
    float s[8];
    {
      const float* kp = kT + ((size_t)b * NN + j0 + sgu * 8) * DQK;
#pragma unroll
      for (int jj = 0; jj < 8; ++jj) {
        float sum = 0.f;
#pragma unroll
        for (int o = 0; o < DQK; ++o) sum += qreg[o] * kp[jj * DQK + o];
        s[jj] = sum;
      }
    }

    // online softmax across the 4 waves that share each row
    float pm = -1e30f;
#pragma unroll
    for (int jj = 0; jj < 8; ++jj) pm = fmaxf(pm, s[jj]);
    red[t] = pm;
    __syncthreads();  // bar1
    const float tmax = fmaxf(fmaxf(red[sm], red[sm + 64]),
                             fmaxf(red[sm + 128], red[sm + 192]));
    const float mold = mrow[sm];
    const float mnew = fmaxf(mold, tmax);
    float psum = 0.f;
#pragma unroll
    for (int jj = 0; jj < 8; ++jj) {
      const float p = __expf(s[jj] - mnew);
      s[jj] = p;
      psum += p;
    }
    __syncthreads();  // bar2 (red reads done)
    red[t] = psum;
    __syncthreads();  // bar3
    if (t < MT) {
      const float ts = red[t] + red[t + 64] + red[t + 128] + red[t + 192];
      const float alpha = __expf(mold - mnew);  // first tile: exp(-1e30-*)=0
      mrow[t] = mnew;
      lrow[t] = lrow[t] * alpha + ts;
      arow[t] = alpha;
    }
    // write P tile (2-way-bank-safe b64 writes)
    {
      float* pp = &Ps[sm * PSTR + sgu * 8];
#pragma unroll
      for (int jj = 0; jj < 8; jj += 2)
        *(float2*)(pp + jj) = make_float2(s[jj], s[jj + 1]);
    }
    __syncthreads();  // bar4: Ps/arow visible

    // PV: thread tile 8m x 8c, b64 LDS reads (conflict-free)
    {
      float av[8];
#pragma unroll
      for (int im = 0; im < 8; ++im) av[im] = arow[tm * 8 + im];
#pragma unroll
      for (int im = 0; im < 8; ++im)
#pragma unroll
        for (int ic = 0; ic < 8; ++ic) oacc[im][ic] *= av[im];

#pragma unroll 2
      for (int jp = 0; jp < JT; jp += 2) {
        float2 pv[8], vv2[8];
#pragma unroll
        for (int im = 0; im < 8; ++im)
          pv[im] = *(const float2*)&Ps[(tm * 8 + im) * PSTR + jp];
#pragma unroll
        for (int ic = 0; ic < 8; ++ic)
          vv2[ic] = *(const float2*)&Vs[(tc + 32 * ic) * VSTR + jp];
#pragma unroll
        for (int im = 0; im < 8; ++im)
#pragma unroll
          for (int ic = 0; ic < 8; ++ic)
            oacc[im][ic] += pv[im].x * vv2[ic].x + pv[im].y * vv2[ic].y;
      }
    }
  }

  // epilogue: out[b][c][m] = gamma * (O/l) + x[b][c][m]
  const float g0 = gamma[0];
#pragma unroll
  for (int im = 0; im < 8; ++im) {
    const int m = m0 + tm * 8 + im;
    const float linv = 1.f / lrow[tm * 8 + im];
#pragma unroll
    for (int ic = 0; ic < 8; ++ic) {
      const int c = tc + 32 * ic;
      const size_t idx = ((size_t)b * NC + c) * NN + m;
      out[idx] = g0 * (oacc[im][ic] * linv) + x[idx];
    }
  }
}

extern "C" void kernel_launch(void* const* d_in, const int* in_sizes, int n_in,
                              void* d_out, int out_size, void* d_ws, size_t ws_size,
                              hipStream_t stream) {
  const float* x     = (const float*)d_in[0];
  const float* Wq    = (const float*)d_in[1];
  const float* bq    = (const float*)d_in[2];
  const float* Wk    = (const float*)d_in[3];
  const float* bk    = (const float*)d_in[4];
  const float* Wv    = (const float*)d_in[5];
  const float* bv    = (const float*)d_in[6];
  const float* gamma = (const float*)d_in[7];
  float* out = (float*)d_out;

  float* q  = (float*)d_ws;                       // [B][N][32]
  float* kT = q  + (size_t)NB * NN * DQK;         // [B][N][32]  (k columns)
  float* v  = kT + (size_t)NB * NN * DQK;         // [B][C][N]
  // total ws use: 2*0.5M + 4M floats = 21 MB

  proj_qk_kernel<<<dim3(NN / 64, NB), dim3(256), 0, stream>>>(x, Wq, bq, Wk, bk, q, kT);
  proj_v_kernel<<<dim3(NN / 64, NC / 64, NB), dim3(256), 0, stream>>>(x, Wv, bv, v);
  flash_kernel<<<dim3(NN / MT, NB), dim3(256), 0, stream>>>(q, kT, v, x, gamma, out);
}

// Round 2
// 285.714 us; speedup vs baseline: 6.2265x; 6.2265x over previous
//
#include <hip/hip_runtime.h>
#include <hip/hip_bf16.h>
#include <cstddef>

#define NB  4
#define NC  256
#define NN  4096
#define DQK 32
#define MT  64      // query rows per block
#define JT  64      // key tile per iteration
#define SSTR 68     // Ss row stride in fp32 words (272 B rows; 4m-bank pattern, <=2-way)
#define VSTR 72     // Vs row stride in bf16 elems (144 B rows; <=2-way both ways)

typedef __attribute__((ext_vector_type(8))) short short8;
typedef __attribute__((ext_vector_type(4))) float f32x4;

#define MFMA16(a, b, c) __builtin_amdgcn_mfma_f32_16x16x32_bf16((a), (b), (c), 0, 0, 0)

__device__ inline unsigned pk2bf(float a, float b) {
  __hip_bfloat162 h = __float22bfloat162_rn(make_float2(a, b));
  unsigned u;
  __builtin_memcpy(&u, &h, 4);
  return u;
}

// ---------------- q/k projections -> bf16 q[b][n][32], kT[b][n][32] ----------------
__global__ __launch_bounds__(256) void proj_qk_kernel(
    const float* __restrict__ x, const float* __restrict__ Wq,
    const float* __restrict__ bq, const float* __restrict__ Wk,
    const float* __restrict__ bk, __hip_bfloat16* __restrict__ q,
    __hip_bfloat16* __restrict__ kT) {
  const int t = threadIdx.x;
  const int b = blockIdx.y;
  const int n = blockIdx.x * 64 + (t & 63);
  const int g = __builtin_amdgcn_readfirstlane(t >> 6);   // 0,1: q ; 2,3: k
  const float* W    = (g < 2) ? Wq : Wk;
  const float* bias = (g < 2) ? bq : bk;
  const int obase = (g & 1) * 16;

  float acc[16];
#pragma unroll
  for (int i = 0; i < 16; ++i) acc[i] = bias[obase + i];

  const float* xp = x + ((size_t)b * NC) * NN + n;
#pragma unroll 4
  for (int c = 0; c < NC; ++c) {
    float xv = xp[(size_t)c * NN];
#pragma unroll
    for (int i = 0; i < 16; ++i) acc[i] += W[(obase + i) * NC + c] * xv;
  }
  __hip_bfloat16* dst = ((g < 2) ? q : kT) + ((size_t)b * NN + n) * DQK + obase;
  unsigned p[8];
#pragma unroll
  for (int i = 0; i < 8; ++i) p[i] = pk2bf(acc[2 * i], acc[2 * i + 1]);
  ((uint4*)dst)[0] = make_uint4(p[0], p[1], p[2], p[3]);
  ((uint4*)dst)[1] = make_uint4(p[4], p[5], p[6], p[7]);
}

// ---------------- v projection -> bf16 v[b][c][n] ----------------
__global__ __launch_bounds__(256) void proj_v_kernel(
    const float* __restrict__ x, const float* __restrict__ Wv,
    const float* __restrict__ bv, __hip_bfloat16* __restrict__ v) {
  const int t = threadIdx.x;
  const int b = blockIdx.z;
  const int n = blockIdx.x * 64 + (t & 63);
  const int g = __builtin_amdgcn_readfirstlane(t >> 6);
  const int obase = blockIdx.y * 64 + g * 16;

  float acc[16];
#pragma unroll
  for (int i = 0; i < 16; ++i) acc[i] = bv[obase + i];

  const float* xp = x + ((size_t)b * NC) * NN + n;
#pragma unroll 4
  for (int c = 0; c < NC; ++c) {
    float xv = xp[(size_t)c * NN];
#pragma unroll
    for (int i = 0; i < 16; ++i) acc[i] += Wv[(obase + i) * NC + c] * xv;
  }
#pragma unroll
  for (int i = 0; i < 16; ++i)
    v[((size_t)b * NC + obase + i) * NN + n] = __hip_bfloat16(acc[i]);
}

// ---------------- MFMA flash attention + gamma*out + x ----------------
__global__ __launch_bounds__(256) void flash_kernel(
    const __hip_bfloat16* __restrict__ q, const __hip_bfloat16* __restrict__ kt,
    const __hip_bfloat16* __restrict__ v, const float* __restrict__ x,
    const float* __restrict__ gamma, float* __restrict__ out) {
  __shared__ float Ss[MT * SSTR];            // 17408 B; doubles as P bf16 (row stride 272 B)
  __shared__ __hip_bfloat16 Vs[NC * VSTR];   // 36864 B
  __shared__ float2 red2[256];               // 2048 B
  __shared__ float mrow[MT], lrow[MT], arow[MT];

  const int t = threadIdx.x;
  // XCD swizzle: 2 XCDs per batch -> per-XCD V working set = 2 MB (fits 4 MB L2)
  const int flat = blockIdx.x;
  const int b    = (flat & 7) >> 1;
  const int m0   = ((flat >> 3) * 2 + (flat & 1)) * MT;

  const int w    = __builtin_amdgcn_readfirstlane(t >> 6);  // wave id 0..3
  const int ln   = t & 15;
  const int quad = (t & 63) >> 4;

  // Q A-fragments resident in registers (4 m-tiles x full d=32)
  short8 qa[4];
  {
    const __hip_bfloat16* qp = q + ((size_t)b * NN + m0) * DQK;
#pragma unroll
    for (int mt = 0; mt < 4; ++mt)
      qa[mt] = *(const short8*)(qp + (mt * 16 + ln) * DQK + quad * 8);
  }
  if (t < MT) { mrow[t] = -3.0e38f; lrow[t] = 0.f; }

  f32x4 zero4 = {0.f, 0.f, 0.f, 0.f};
  f32x4 acc[4][4];   // [ctile][mtile] of O' = V . P^T  (row=c, col=m)
#pragma unroll
  for (int ct = 0; ct < 4; ++ct)
#pragma unroll
    for (int mt = 0; mt < 4; ++mt) acc[ct][mt] = zero4;

  const int c0 = w * 64;   // this wave's c-range in PV
  const int sm = t >> 2;   // softmax row
  const int sc = t & 3;    // softmax chunk (16 j each)

  for (int j0 = 0; j0 < NN; j0 += JT) {
    __syncthreads();  // barA: prior PV reads of Vs/P done

    // ---- stage V tile [256c x 64j] -> LDS (coalesced 16B global reads) ----
    {
      const __hip_bfloat16* vb = v + ((size_t)b * NC) * NN + j0;
      int c = t >> 3;
      const int jj = (t & 7) * 8;
#pragma unroll
      for (int p = 0; p < 8; ++p, c += 32)
        *(uint4*)&Vs[c * VSTR + jj] = *(const uint4*)(vb + (size_t)c * NN + jj);
    }

    // ---- S = Q . K^T : one MFMA per m-tile (K=32 = full d) ----
    {
      short8 kb = *(const short8*)(kt + ((size_t)b * NN + j0 + w * 16 + ln) * DQK + quad * 8);
      f32x4 sf[4];
#pragma unroll
      for (int mt = 0; mt < 4; ++mt) sf[mt] = MFMA16(qa[mt], kb, zero4);
      // C-frag: col(j) = ln, row(m) = quad*4 + r
#pragma unroll
      for (int mt = 0; mt < 4; ++mt)
#pragma unroll
        for (int r = 0; r < 4; ++r)
          Ss[(mt * 16 + quad * 4 + r) * SSTR + w * 16 + ln] = sf[mt][r];
    }
    __syncthreads();  // bar1: Ss + Vs visible

    // ---- softmax pass 1: per-chunk max + exp + sum ----
    float e[16];
    float cm;
    {
      const float4* srow = (const float4*)&Ss[sm * SSTR + sc * 16];
      float4 s0 = srow[0], s1 = srow[1], s2 = srow[2], s3 = srow[3];
      float sv[16] = {s0.x, s0.y, s0.z, s0.w, s1.x, s1.y, s1.z, s1.w,
                      s2.x, s2.y, s2.z, s2.w, s3.x, s3.y, s3.z, s3.w};
      cm = sv[0];
#pragma unroll
      for (int i = 1; i < 16; ++i) cm = fmaxf(cm, sv[i]);
      float cs = 0.f;
#pragma unroll
      for (int i = 0; i < 16; ++i) { e[i] = __expf(sv[i] - cm); cs += e[i]; }
      red2[t] = make_float2(cm, cs);
    }
    __syncthreads();  // bar2: red2 visible; pass-1 Ss reads complete

    // ---- softmax pass 2: cross-chunk combine, write P (bf16, over Ss) ----
    {
      const float m_old = mrow[sm];      // same-wave threads: reads precede the write below
      const float l_old = lrow[sm];
      float2 rr[4];
#pragma unroll
      for (int i = 0; i < 4; ++i) rr[i] = red2[sm * 4 + i];
      float mnew = m_old;
#pragma unroll
      for (int i = 0; i < 4; ++i) mnew = fmaxf(mnew, rr[i].x);
      float ts = 0.f;
#pragma unroll
      for (int i = 0; i < 4; ++i) ts += rr[i].y * __expf(rr[i].x - mnew);
      const float alpha = __expf(m_old - mnew);
      if (sc == 0) { mrow[sm] = mnew; lrow[sm] = l_old * alpha + ts; arow[sm] = alpha; }
      const float scale = __expf(cm - mnew);
      unsigned p[8];
#pragma unroll
      for (int i = 0; i < 8; ++i)
        p[i] = pk2bf(e[2 * i] * scale, e[2 * i + 1] * scale);
      uint4* pd = (uint4*)((char*)Ss + sm * (SSTR * 4) + sc * 32);
      pd[0] = make_uint4(p[0], p[1], p[2], p[3]);
      pd[1] = make_uint4(p[4], p[5], p[6], p[7]);
    }
    __syncthreads();  // bar3: P + arow visible

    // ---- PV: O'[c][m] += V . P^T, per wave 64c x 64m ----
    {
      float av[4];
#pragma unroll
      for (int mt = 0; mt < 4; ++mt) av[mt] = arow[mt * 16 + ln];
#pragma unroll
      for (int ct = 0; ct < 4; ++ct)
#pragma unroll
        for (int mt = 0; mt < 4; ++mt) acc[ct][mt] *= av[mt];

#pragma unroll
      for (int ks = 0; ks < 2; ++ks) {
        short8 va[4], pb[4];
#pragma unroll
        for (int ct = 0; ct < 4; ++ct)
          va[ct] = *(const short8*)&Vs[(c0 + ct * 16 + ln) * VSTR + ks * 32 + quad * 8];
#pragma unroll
        for (int mt = 0; mt < 4; ++mt)
          pb[mt] = *(const short8*)((const char*)Ss +
                     (mt * 16 + ln) * (SSTR * 4) + (ks * 32 + quad * 8) * 2);
#pragma unroll
        for (int ct = 0; ct < 4; ++ct)
#pragma unroll
          for (int mt = 0; mt < 4; ++mt)
            acc[ct][mt] = MFMA16(va[ct], pb[mt], acc[ct][mt]);
      }
    }
  }

  // ---- epilogue: out[b][c][m] = gamma*(O'/l) + x  (coalesced in m) ----
  const float g0 = gamma[0];
  float li[4];
#pragma unroll
  for (int mt = 0; mt < 4; ++mt) li[mt] = 1.f / lrow[mt * 16 + ln];
#pragma unroll
  for (int ct = 0; ct < 4; ++ct) {
#pragma unroll
    for (int r = 0; r < 4; ++r) {
      const int c = c0 + ct * 16 + quad * 4 + r;
      const float* xr = x + ((size_t)b * NC + c) * NN + m0;
      float* orow = out + ((size_t)b * NC + c) * NN + m0;
#pragma unroll
      for (int mt = 0; mt < 4; ++mt) {
        const int m = mt * 16 + ln;
        orow[m] = g0 * (acc[ct][mt][r] * li[mt]) + xr[m];
      }
    }
  }
}

extern "C" void kernel_launch(void* const* d_in, const int* in_sizes, int n_in,
                              void* d_out, int out_size, void* d_ws, size_t ws_size,
                              hipStream_t stream) {
  const float* x     = (const float*)d_in[0];
  const float* Wq    = (const float*)d_in[1];
  const float* bq    = (const float*)d_in[2];
  const float* Wk    = (const float*)d_in[3];
  const float* bk    = (const float*)d_in[4];
  const float* Wv    = (const float*)d_in[5];
  const float* bv    = (const float*)d_in[6];
  const float* gamma = (const float*)d_in[7];
  float* out = (float*)d_out;

  __hip_bfloat16* q  = (__hip_bfloat16*)d_ws;               // [B][N][32] bf16
  __hip_bfloat16* kT = q  + (size_t)NB * NN * DQK;          // [B][N][32] bf16
  __hip_bfloat16* v  = kT + (size_t)NB * NN * DQK;          // [B][C][N]  bf16
  // ws use: 1 MB + 1 MB + 8 MB = 10 MB

  proj_qk_kernel<<<dim3(NN / 64, NB), dim3(256), 0, stream>>>(x, Wq, bq, Wk, bk, q, kT);
  proj_v_kernel<<<dim3(NN / 64, NC / 64, NB), dim3(256), 0, stream>>>(x, Wv, bv, v);
  flash_kernel<<<dim3(NB * NN / MT), dim3(256), 0, stream>>>(q, kT, v, x, gamma, out);
}